// Round 1
// baseline (154.778 us; speedup 1.0000x reference)
//
#include <hip/hip_runtime.h>

#define NB 4
#define NV 6890
#define HH 64
#define WW 64
#define HW 4096
#define NPAD 6912
#define NF4 3445          // float4 (=2 verts) per batch
#define VC 8              // vertex chunks for term1
#define CS 431            // float4 per chunk (8*431=3448 >= 3445)
#define PC 4              // row chunks for term2 (16 rows each)
#define NRED_BLOCKS 172   // (16384 + 27648) / 256

// ws byte offsets
#define OFF_MASK 0                      // NB*64 u64  = 2048 B
#define OFF_T1   2048                   // 16384 u32  = 65536 B
#define OFF_T2   (2048 + 65536)         // NB*NPAD u32 = 110592 B
#define OFF_PART (2048 + 65536 + 110592)

#define FLT_MAX_BITS 0x7F7FFFFFu

// ---------------------------------------------------------------------------
// Pre-pass: build per-row 64-bit validity masks; init min arrays to +FLT_MAX.
__global__ __launch_bounds__(256) void k_pre(const int* __restrict__ mask,
                                             unsigned long long* __restrict__ bm,
                                             unsigned* __restrict__ t1,
                                             unsigned* __restrict__ t2) {
    int gid = blockIdx.x * 256 + threadIdx.x;   // 0..16383, lane == x coordinate
    int val = mask[gid] > 0;
    unsigned long long bal = __ballot(val);
    if ((threadIdx.x & 63) == 0) bm[gid >> 6] = bal;   // (b*64 + y)
    t1[gid] = FLT_MAX_BITS;
    t2[gid] = FLT_MAX_BITS;
    if (gid < NB * NPAD - HW * NB)                      // remaining 11264 entries
        t2[gid + HW * NB] = FLT_MAX_BITS;
}

// ---------------------------------------------------------------------------
// Term1: per-pixel min over a chunk of vertices. thread = pixel, verts uniform
// (b derived from blockIdx only -> scalar loads of vertex float4 = 2 verts).
__global__ __launch_bounds__(256) void k_t1(const float* __restrict__ vert,
                                            unsigned* __restrict__ t1) {
    int b   = blockIdx.x >> 4;                        // uniform per block
    int pix = ((blockIdx.x & 15) << 8) | threadIdx.x;
    float fx = (float)(pix & 63);
    float fy = (float)(pix >> 6);
    const float4* v4 = reinterpret_cast<const float4*>(vert) + b * NF4;
    int i0 = blockIdx.y * CS;
    int i1 = i0 + CS; if (i1 > NF4) i1 = NF4;
    float m = 3.402823466e38f;
    #pragma unroll 4
    for (int i = i0; i < i1; ++i) {
        float4 q = v4[i];                              // verts 2i, 2i+1 (x,y,x,y)
        float dx0 = fx - q.x, dy0 = fy - q.y;
        float dx1 = fx - q.z, dy1 = fy - q.w;
        float t0 = fmaf(dx0, dx0, dy0 * dy0);
        float u1 = fmaf(dx1, dx1, dy1 * dy1);
        m = fminf(m, fminf(t0, u1));                   // v_min3
    }
    atomicMin(&t1[(b << 12) | pix], __float_as_uint(m));
}

// ---------------------------------------------------------------------------
// Term2: per-vertex min over valid pixels of a 16-row band. Bitmask iteration:
// bits are wave-uniform -> scalar ff1/clear; VALU only for cvt/sub/fma/min.
__global__ __launch_bounds__(256) void k_t2(const float* __restrict__ vert,
                                            const unsigned long long* __restrict__ bm,
                                            unsigned* __restrict__ t2) {
    int n = blockIdx.x * 256 + threadIdx.x;
    if (n >= NV) return;
    int b = blockIdx.y;
    float vx = vert[(b * NV + n) * 2];
    float vy = vert[(b * NV + n) * 2 + 1];
    int y0 = blockIdx.z * (HH / PC);
    float m = 3.402823466e38f;
    for (int y = y0; y < y0 + HH / PC; ++y) {
        unsigned long long bits = bm[b * 64 + y];
        float dy = vy - (float)y;
        float rc = dy * dy;
        while (bits) {
            int x = __builtin_ctzll(bits);
            bits &= bits - 1;
            float dx = vx - (float)x;
            m = fminf(m, fmaf(dx, dx, rc));
        }
    }
    atomicMin(&t2[b * NPAD + n], __float_as_uint(m));
}

// ---------------------------------------------------------------------------
// Reduce stage 1: sqrt + scale + mask, block-reduce to partials.
__global__ __launch_bounds__(256) void k_red1(const unsigned* __restrict__ t1,
                                              const unsigned* __restrict__ t2,
                                              const int* __restrict__ mask,
                                              float* __restrict__ part) {
    int gid = blockIdx.x * 256 + threadIdx.x;   // 0..44031
    float v = 0.f;
    if (gid < HW * NB) {
        if (mask[gid] > 0)
            v = sqrtf(__uint_as_float(t1[gid])) * (1.0f / 64.0f);
    } else {
        int j = gid - HW * NB;                  // 0..27647
        int bb = j / NPAD;
        int n  = j - bb * NPAD;
        if (n < NV)
            v = sqrtf(__uint_as_float(t2[j])) * (1.0f / 64.0f);
    }
    __shared__ float sbuf[4];
    for (int off = 32; off; off >>= 1) v += __shfl_down(v, off, 64);
    int lane = threadIdx.x & 63, wid = threadIdx.x >> 6;
    if (!lane) sbuf[wid] = v;
    __syncthreads();
    if (wid == 0) {
        v = (lane < 4) ? sbuf[lane] : 0.f;
        v += __shfl_down(v, 2, 64);
        v += __shfl_down(v, 1, 64);
        if (!lane) part[blockIdx.x] = v;
    }
}

// Reduce stage 2: sum partials, write scalar output (plain store, no init needed).
__global__ __launch_bounds__(256) void k_red2(const float* __restrict__ part,
                                              float* __restrict__ out) {
    float v = (threadIdx.x < NRED_BLOCKS) ? part[threadIdx.x] : 0.f;
    __shared__ float sbuf[4];
    for (int off = 32; off; off >>= 1) v += __shfl_down(v, off, 64);
    int lane = threadIdx.x & 63, wid = threadIdx.x >> 6;
    if (!lane) sbuf[wid] = v;
    __syncthreads();
    if (threadIdx.x == 0) {
        v = sbuf[0] + sbuf[1] + sbuf[2] + sbuf[3];
        out[0] = v;
    }
}

extern "C" void kernel_launch(void* const* d_in, const int* in_sizes, int n_in,
                              void* d_out, int out_size, void* d_ws, size_t ws_size,
                              hipStream_t stream) {
    const float* vert = (const float*)d_in[0];
    const int*   mask = (const int*)d_in[1];
    char* ws = (char*)d_ws;
    unsigned long long* bm = (unsigned long long*)(ws + OFF_MASK);
    unsigned* t1  = (unsigned*)(ws + OFF_T1);
    unsigned* t2  = (unsigned*)(ws + OFF_T2);
    float*    prt = (float*)(ws + OFF_PART);
    float*    out = (float*)d_out;

    k_pre <<<64, 256, 0, stream>>>(mask, bm, t1, t2);
    k_t1  <<<dim3(64, VC), 256, 0, stream>>>(vert, t1);
    k_t2  <<<dim3(27, NB, PC), 256, 0, stream>>>(vert, bm, t2);
    k_red1<<<NRED_BLOCKS, 256, 0, stream>>>(t1, t2, mask, prt);
    k_red2<<<1, 256, 0, stream>>>(prt, out);
}

// Round 2
// 112.243 us; speedup vs baseline: 1.3789x; 1.3789x over previous
//
#include <hip/hip_runtime.h>

#define NB 4
#define NV 6890
#define HW 4096
#define NPAD 6912
#define VC 32             // vertex chunks for term1
#define CS 216            // verts per chunk (32*216 = 6912 >= 6890)
#define PC2 10            // pixel-list chunks for term2
#define NRED_BLOCKS 172   // (16384 + 27648) / 256

// ws byte offsets (16B aligned)
#define OFF_VT   0                       // NB*NV float4 (-2vx,-2vy,v.v,0) = 440960 B
#define OFF_PL   440960                  // NB*4096 float4 (-2px,-2py,p.p,0) = 262144 B
#define OFF_T1   703104                  // 16384 u32
#define OFF_T2   768640                  // NB*NPAD u32 = 110592 B
#define OFF_CNT  879232                  // NB u32
#define OFF_PART 879248                  // NRED_BLOCKS f32

#define FLT_MAX_BITS 0x7F7FFFFFu
#define FINF 3.402823466e38f

// ---------------------------------------------------------------------------
// Vertex prepass: vt[g] = (-2vx, -2vy, v.v, 0); also init t2 to FLT_MAX.
// grid 108 x 256 = 27648 == NB*NPAD exactly.
__global__ __launch_bounds__(256) void k_vprep(const float* __restrict__ vert,
                                               float4* __restrict__ vt,
                                               unsigned* __restrict__ t2) {
    int gid = blockIdx.x * 256 + threadIdx.x;
    t2[gid] = FLT_MAX_BITS;
    if (gid < NB * NV) {
        float2 v = reinterpret_cast<const float2*>(vert)[gid];
        vt[gid] = make_float4(-2.f * v.x, -2.f * v.y, fmaf(v.x, v.x, v.y * v.y), 0.f);
    }
}

// ---------------------------------------------------------------------------
// Pixel prepass: one block per batch. Compact valid pixels into
// pl[b*4096 + k] = (-2px, -2py, p.p, 0); write count; init t1.
__global__ __launch_bounds__(256) void k_pprep(const int* __restrict__ mask,
                                               float4* __restrict__ pl,
                                               unsigned* __restrict__ cnt,
                                               unsigned* __restrict__ t1) {
    int b = blockIdx.x;
    __shared__ unsigned wcnt[4];
    __shared__ unsigned base_s;
    if (threadIdx.x == 0) base_s = 0;
    __syncthreads();
    unsigned lane = threadIdx.x & 63, wid = threadIdx.x >> 6;
    for (int pass = 0; pass < 16; ++pass) {
        int pix = pass * 256 + threadIdx.x;
        t1[b * HW + pix] = FLT_MAX_BITS;
        int valid = mask[b * HW + pix] > 0;
        unsigned long long bal = __ballot(valid);
        unsigned inwave = __popcll(bal & ((1ull << lane) - 1ull));
        if (lane == 0) wcnt[wid] = (unsigned)__popcll(bal);
        __syncthreads();
        unsigned pre = base_s;
        for (unsigned w = 0; w < wid; ++w) pre += wcnt[w];
        if (valid) {
            float fx = (float)(pix & 63), fy = (float)(pix >> 6);
            pl[b * HW + pre + inwave] =
                make_float4(-2.f * fx, -2.f * fy, fmaf(fx, fx, fy * fy), 0.f);
        }
        __syncthreads();
        if (threadIdx.x == 0) base_s += wcnt[0] + wcnt[1] + wcnt[2] + wcnt[3];
        __syncthreads();
    }
    if (threadIdx.x == 0) cnt[b] = base_s;
}

// ---------------------------------------------------------------------------
// Term1: thread = pixel, loop over a vertex chunk (uniform scalar float4
// loads). 2 FMA + min per vert, paired accumulators for ILP.
__global__ __launch_bounds__(256) void k_t1(const float4* __restrict__ vt,
                                            unsigned* __restrict__ t1) {
    int b   = blockIdx.x >> 4;                      // uniform
    int pix = ((blockIdx.x & 15) << 8) | threadIdx.x;
    float fx = (float)(pix & 63), fy = (float)(pix >> 6);
    const float4* v4 = vt + b * NV;
    int i0 = blockIdx.y * CS;
    int i1 = i0 + CS; if (i1 > NV) i1 = NV;
    float m0 = FINF, m1 = FINF;
    int i = i0;
    #pragma unroll 4
    for (; i + 2 <= i1; i += 2) {
        float4 a = v4[i], c = v4[i + 1];
        m0 = fminf(m0, fmaf(a.x, fx, fmaf(a.y, fy, a.z)));
        m1 = fminf(m1, fmaf(c.x, fx, fmaf(c.y, fy, c.z)));
    }
    if (i < i1) {
        float4 a = v4[i];
        m0 = fminf(m0, fmaf(a.x, fx, fmaf(a.y, fy, a.z)));
    }
    float m = fminf(m0, m1) + fmaf(fx, fx, fy * fy);
    m = fmaxf(m, 0.f);                              // keep uint-min ordering valid
    atomicMin(&t1[(b << 12) | pix], __float_as_uint(m));
}

// ---------------------------------------------------------------------------
// Term2: thread = vertex, loop over a chunk of the compacted valid-pixel
// list (uniform scalar float4 loads). Same inner form as k_t1.
__global__ __launch_bounds__(256) void k_t2(const float* __restrict__ vert,
                                            const float4* __restrict__ pl,
                                            const unsigned* __restrict__ cnt,
                                            unsigned* __restrict__ t2) {
    int n = blockIdx.x * 256 + threadIdx.x;
    if (n >= NV) return;
    int b = blockIdx.y;
    float2 v = reinterpret_cast<const float2*>(vert)[b * NV + n];
    int count = (int)cnt[b];
    int per = (count + PC2 - 1) / PC2;
    int j0 = blockIdx.z * per;
    int j1 = j0 + per; if (j1 > count) j1 = count;
    const float4* p4 = pl + b * HW;
    float m0 = FINF, m1 = FINF;
    int j = j0;
    #pragma unroll 4
    for (; j + 2 <= j1; j += 2) {
        float4 a = p4[j], c = p4[j + 1];
        m0 = fminf(m0, fmaf(a.x, v.x, fmaf(a.y, v.y, a.z)));
        m1 = fminf(m1, fmaf(c.x, v.x, fmaf(c.y, v.y, c.z)));
    }
    if (j < j1) {
        float4 a = p4[j];
        m0 = fminf(m0, fmaf(a.x, v.x, fmaf(a.y, v.y, a.z)));
    }
    float m = fminf(m0, m1) + fmaf(v.x, v.x, v.y * v.y);
    m = fmaxf(m, 0.f);
    atomicMin(&t2[b * NPAD + n], __float_as_uint(m));
}

// ---------------------------------------------------------------------------
// Reduce stage 1: sqrt + scale + mask, block-reduce to partials.
__global__ __launch_bounds__(256) void k_red1(const unsigned* __restrict__ t1,
                                              const unsigned* __restrict__ t2,
                                              const int* __restrict__ mask,
                                              float* __restrict__ part) {
    int gid = blockIdx.x * 256 + threadIdx.x;   // 0..44031
    float v = 0.f;
    if (gid < HW * NB) {
        if (mask[gid] > 0)
            v = sqrtf(__uint_as_float(t1[gid])) * (1.0f / 64.0f);
    } else {
        int j = gid - HW * NB;                  // 0..27647
        int bb = j / NPAD;
        int n  = j - bb * NPAD;
        if (n < NV)
            v = sqrtf(__uint_as_float(t2[j])) * (1.0f / 64.0f);
    }
    __shared__ float sbuf[4];
    for (int off = 32; off; off >>= 1) v += __shfl_down(v, off, 64);
    int lane = threadIdx.x & 63, wid = threadIdx.x >> 6;
    if (!lane) sbuf[wid] = v;
    __syncthreads();
    if (wid == 0) {
        v = (lane < 4) ? sbuf[lane] : 0.f;
        v += __shfl_down(v, 2, 64);
        v += __shfl_down(v, 1, 64);
        if (!lane) part[blockIdx.x] = v;
    }
}

// Reduce stage 2: sum partials, write scalar output.
__global__ __launch_bounds__(256) void k_red2(const float* __restrict__ part,
                                              float* __restrict__ out) {
    float v = (threadIdx.x < NRED_BLOCKS) ? part[threadIdx.x] : 0.f;
    __shared__ float sbuf[4];
    for (int off = 32; off; off >>= 1) v += __shfl_down(v, off, 64);
    int lane = threadIdx.x & 63, wid = threadIdx.x >> 6;
    if (!lane) sbuf[wid] = v;
    __syncthreads();
    if (threadIdx.x == 0) out[0] = sbuf[0] + sbuf[1] + sbuf[2] + sbuf[3];
}

extern "C" void kernel_launch(void* const* d_in, const int* in_sizes, int n_in,
                              void* d_out, int out_size, void* d_ws, size_t ws_size,
                              hipStream_t stream) {
    const float* vert = (const float*)d_in[0];
    const int*   mask = (const int*)d_in[1];
    char* ws = (char*)d_ws;
    float4*   vt  = (float4*)(ws + OFF_VT);
    float4*   pl  = (float4*)(ws + OFF_PL);
    unsigned* t1  = (unsigned*)(ws + OFF_T1);
    unsigned* t2  = (unsigned*)(ws + OFF_T2);
    unsigned* cnt = (unsigned*)(ws + OFF_CNT);
    float*    prt = (float*)(ws + OFF_PART);
    float*    out = (float*)d_out;

    k_vprep<<<108, 256, 0, stream>>>(vert, vt, t2);
    k_pprep<<<NB, 256, 0, stream>>>(mask, pl, cnt, t1);
    k_t1  <<<dim3(64, VC), 256, 0, stream>>>(vt, t1);
    k_t2  <<<dim3(27, NB, PC2), 256, 0, stream>>>(vert, pl, cnt, t2);
    k_red1<<<NRED_BLOCKS, 256, 0, stream>>>(t1, t2, mask, prt);
    k_red2<<<1, 256, 0, stream>>>(prt, out);
}

// Round 3
// 108.684 us; speedup vs baseline: 1.4241x; 1.0327x over previous
//
#include <hip/hip_runtime.h>

#define NB 4
#define NV 6890
#define HW 4096
#define NPAD 6912
#define VC 32             // vertex chunks for term1
#define CS 216            // verts per chunk (32*216 = 6912 >= 6890)
#define PC2 10            // pixel chunks for term2
#define PCS 410           // pixels per chunk (10*410 = 4100 >= 4096)
#define T1_BLOCKS 2048    // 4 batches * 16 pixel-blocks * 32 chunks
#define T2_BLOCKS 1080    // 27 vert-blocks * 4 batches * 10 chunks
#define NRED_BLOCKS 172   // (16384 + 27648) / 256

// ws byte offsets (16B aligned)
#define OFF_VT   0                       // NB*NV float4 (-2vx,-2vy,v.v,0) = 440960 B
#define OFF_PL   440960                  // NB*HW float4 (-2px,-2py,pp|BIG,0) = 262144 B
#define OFF_T1   703104                  // 16384 u32
#define OFF_T2   768640                  // NB*NPAD u32 = 110592 B
#define OFF_PART 879232                  // NRED_BLOCKS f32

#define FLT_MAX_BITS 0x7F7FFFFFu
#define FINF 3.402823466e38f
#define PBIG 1.0e18f

// ---------------------------------------------------------------------------
// Fused prep: grid 108x256 = 27648 threads.
//  - t2 init (27648), vt build (27560)
//  - t1 init + pixel table with BIG sentinel for invalid pixels (16384)
__global__ __launch_bounds__(256) void k_prep(const float* __restrict__ vert,
                                              const int* __restrict__ mask,
                                              float4* __restrict__ vt,
                                              float4* __restrict__ pl,
                                              unsigned* __restrict__ t1,
                                              unsigned* __restrict__ t2) {
    int gid = blockIdx.x * 256 + threadIdx.x;
    t2[gid] = FLT_MAX_BITS;
    if (gid < NB * NV) {
        float2 v = reinterpret_cast<const float2*>(vert)[gid];
        vt[gid] = make_float4(-2.f * v.x, -2.f * v.y, fmaf(v.x, v.x, v.y * v.y), 0.f);
    }
    if (gid < NB * HW) {
        t1[gid] = FLT_MAX_BITS;
        float fx = (float)(gid & 63), fy = (float)((gid >> 6) & 63);
        float pz = (mask[gid] > 0) ? fmaf(fx, fx, fy * fy) : PBIG;
        pl[gid] = make_float4(-2.f * fx, -2.f * fy, pz, 0.f);
    }
}

// ---------------------------------------------------------------------------
// Fused main: blocks [0,2048) do term1 (thread=pixel, loop verts);
// blocks [2048,3128) do term2 (thread=vertex, loop pixels). Both loops read
// a wave-uniform float4 table (scalar s_loads); 2 FMA + ~0.5 min per eval.
__global__ __launch_bounds__(256) void k_main(const float* __restrict__ vert,
                                              const float4* __restrict__ vt,
                                              const float4* __restrict__ pl,
                                              unsigned* __restrict__ t1,
                                              unsigned* __restrict__ t2) {
    int bx = blockIdx.x;
    if (bx < T1_BLOCKS) {
        int b    = (bx >> 4) & 3;                    // uniform
        int pix  = ((bx & 15) << 8) | threadIdx.x;
        int i0   = (bx >> 6) * CS;
        int i1   = i0 + CS; if (i1 > NV) i1 = NV;
        float fx = (float)(pix & 63), fy = (float)(pix >> 6);
        const float4* v4 = vt + b * NV;
        float m0 = FINF, m1 = FINF;
        int i = i0;
        #pragma unroll 2
        for (; i + 4 <= i1; i += 4) {
            float4 a = v4[i], c = v4[i + 1], e = v4[i + 2], g = v4[i + 3];
            float d0 = fmaf(a.x, fx, fmaf(a.y, fy, a.z));
            float d1 = fmaf(c.x, fx, fmaf(c.y, fy, c.z));
            float d2 = fmaf(e.x, fx, fmaf(e.y, fy, e.z));
            float d3 = fmaf(g.x, fx, fmaf(g.y, fy, g.z));
            m0 = fminf(m0, fminf(d0, d1));           // v_min3
            m1 = fminf(m1, fminf(d2, d3));
        }
        for (; i < i1; ++i) {
            float4 a = v4[i];
            m0 = fminf(m0, fmaf(a.x, fx, fmaf(a.y, fy, a.z)));
        }
        float m = fminf(m0, m1) + fmaf(fx, fx, fy * fy);
        m = fmaxf(m, 0.f);                           // keep uint-min ordering valid
        atomicMin(&t1[(b << 12) | pix], __float_as_uint(m));
    } else {
        int t2id = bx - T1_BLOCKS;                   // [0,1080)
        int nblk = t2id % 27;
        int rest = t2id / 27;
        int b    = rest & 3;
        int j0   = (rest >> 2) * PCS;
        int j1   = j0 + PCS; if (j1 > HW) j1 = HW;
        int n = nblk * 256 + threadIdx.x;
        if (n >= NV) return;
        float2 v = reinterpret_cast<const float2*>(vert)[b * NV + n];
        const float4* p4 = pl + b * HW;
        float m0 = FINF, m1 = FINF;
        int j = j0;
        #pragma unroll 2
        for (; j + 4 <= j1; j += 4) {
            float4 a = p4[j], c = p4[j + 1], e = p4[j + 2], g = p4[j + 3];
            float d0 = fmaf(a.x, v.x, fmaf(a.y, v.y, a.z));
            float d1 = fmaf(c.x, v.x, fmaf(c.y, v.y, c.z));
            float d2 = fmaf(e.x, v.x, fmaf(e.y, v.y, e.z));
            float d3 = fmaf(g.x, v.x, fmaf(g.y, v.y, g.z));
            m0 = fminf(m0, fminf(d0, d1));
            m1 = fminf(m1, fminf(d2, d3));
        }
        for (; j < j1; ++j) {
            float4 a = p4[j];
            m0 = fminf(m0, fmaf(a.x, v.x, fmaf(a.y, v.y, a.z)));
        }
        float m = fminf(m0, m1) + fmaf(v.x, v.x, v.y * v.y);
        m = fmaxf(m, 0.f);
        atomicMin(&t2[b * NPAD + n], __float_as_uint(m));
    }
}

// ---------------------------------------------------------------------------
// Reduce stage 1: sqrt + scale + mask, block-reduce to partials.
__global__ __launch_bounds__(256) void k_red1(const unsigned* __restrict__ t1,
                                              const unsigned* __restrict__ t2,
                                              const int* __restrict__ mask,
                                              float* __restrict__ part) {
    int gid = blockIdx.x * 256 + threadIdx.x;   // 0..44031
    float v = 0.f;
    if (gid < HW * NB) {
        if (mask[gid] > 0)
            v = sqrtf(__uint_as_float(t1[gid])) * (1.0f / 64.0f);
    } else {
        int j = gid - HW * NB;                  // 0..27647
        int bb = j / NPAD;
        int n  = j - bb * NPAD;
        if (n < NV)
            v = sqrtf(__uint_as_float(t2[j])) * (1.0f / 64.0f);
    }
    __shared__ float sbuf[4];
    for (int off = 32; off; off >>= 1) v += __shfl_down(v, off, 64);
    int lane = threadIdx.x & 63, wid = threadIdx.x >> 6;
    if (!lane) sbuf[wid] = v;
    __syncthreads();
    if (wid == 0) {
        v = (lane < 4) ? sbuf[lane] : 0.f;
        v += __shfl_down(v, 2, 64);
        v += __shfl_down(v, 1, 64);
        if (!lane) part[blockIdx.x] = v;
    }
}

// Reduce stage 2: sum partials, write scalar output.
__global__ __launch_bounds__(256) void k_red2(const float* __restrict__ part,
                                              float* __restrict__ out) {
    float v = (threadIdx.x < NRED_BLOCKS) ? part[threadIdx.x] : 0.f;
    __shared__ float sbuf[4];
    for (int off = 32; off; off >>= 1) v += __shfl_down(v, off, 64);
    int lane = threadIdx.x & 63, wid = threadIdx.x >> 6;
    if (!lane) sbuf[wid] = v;
    __syncthreads();
    if (threadIdx.x == 0) out[0] = sbuf[0] + sbuf[1] + sbuf[2] + sbuf[3];
}

extern "C" void kernel_launch(void* const* d_in, const int* in_sizes, int n_in,
                              void* d_out, int out_size, void* d_ws, size_t ws_size,
                              hipStream_t stream) {
    const float* vert = (const float*)d_in[0];
    const int*   mask = (const int*)d_in[1];
    char* ws = (char*)d_ws;
    float4*   vt  = (float4*)(ws + OFF_VT);
    float4*   pl  = (float4*)(ws + OFF_PL);
    unsigned* t1  = (unsigned*)(ws + OFF_T1);
    unsigned* t2  = (unsigned*)(ws + OFF_T2);
    float*    prt = (float*)(ws + OFF_PART);
    float*    out = (float*)d_out;

    k_prep<<<108, 256, 0, stream>>>(vert, mask, vt, pl, t1, t2);
    k_main<<<T1_BLOCKS + T2_BLOCKS, 256, 0, stream>>>(vert, vt, pl, t1, t2);
    k_red1<<<NRED_BLOCKS, 256, 0, stream>>>(t1, t2, mask, prt);
    k_red2<<<1, 256, 0, stream>>>(prt, out);
}

// Round 4
// 76.044 us; speedup vs baseline: 2.0354x; 1.4292x over previous
//
#include <hip/hip_runtime.h>

#define NB 4
#define NV 6890
#define HW 4096
#define NPAD 6912
#define T1_CS 108         // verts per T1 chunk; 64 chunks * 108 = 6912 = NPAD (sentinel-padded)
#define T1_BLOCKS 1024    // 4 batches * 4 row-quarters * 64 chunks
#define T2_BLOCKS 896     // 4 batches * 7 vert-groups * 32 pixel-chunks
#define NRED_BLOCKS 172   // (16384 + 27648) / 256

// ws byte offsets (16B aligned)
#define OFF_VT   0                       // NB*NPAD float4 (-2vx,-2vy,v.v,0 | sentinel) = 442368 B
#define OFF_PL   442368                  // NB*HW float4 (-2px,-2py,pp|BIG,0) = 262144 B
#define OFF_T1   704512                  // 16384 u32
#define OFF_T2   770048                  // NB*NPAD u32 = 110592 B
#define OFF_PART 880640                  // NRED_BLOCKS f32

#define FLT_MAX_BITS 0x7F7FFFFFu
#define FINF 3.402823466e38f
#define PBIG 1.0e18f

// ---------------------------------------------------------------------------
// Fused prep, grid 108x256 = 27648 = NB*NPAD threads.
//  vt[b][n] = (-2vx,-2vy,v.v,0), sentinel (0,0,BIG,0) for n>=NV (kills bounds
//  checks in k_main T1); pl[pix] = (-2px,-2py, valid? p.p : BIG); init t1/t2.
__global__ __launch_bounds__(256) void k_prep(const float* __restrict__ vert,
                                              const int* __restrict__ mask,
                                              float4* __restrict__ vt,
                                              float4* __restrict__ pl,
                                              unsigned* __restrict__ t1,
                                              unsigned* __restrict__ t2) {
    int gid = blockIdx.x * 256 + threadIdx.x;
    t2[gid] = FLT_MAX_BITS;
    int b = gid / NPAD, n = gid - b * NPAD;
    if (n < NV) {
        float2 v = reinterpret_cast<const float2*>(vert)[b * NV + n];
        vt[gid] = make_float4(-2.f * v.x, -2.f * v.y, fmaf(v.x, v.x, v.y * v.y), 0.f);
    } else {
        vt[gid] = make_float4(0.f, 0.f, PBIG, 0.f);
    }
    if (gid < NB * HW) {
        t1[gid] = FLT_MAX_BITS;
        float fx = (float)(gid & 63), fy = (float)((gid >> 6) & 63);
        float pz = (mask[gid] > 0) ? fmaf(fx, fx, fy * fy) : PBIG;
        pl[gid] = make_float4(-2.f * fx, -2.f * fy, pz, 0.f);
    }
}

// ---------------------------------------------------------------------------
// Fused main. T1 blocks: thread owns 4 pixels (same x, rows 4 apart), loops
// LDS-staged vert chunk; shared-x subterm -> 1.75 VALU/eval. T2 blocks:
// thread owns 4 verts, loops LDS-staged pixel chunk -> 2.5 VALU/eval.
__global__ __launch_bounds__(256) void k_main(const float* __restrict__ vert,
                                              const float4* __restrict__ vt,
                                              const float4* __restrict__ pl,
                                              unsigned* __restrict__ t1,
                                              unsigned* __restrict__ t2) {
    __shared__ float4 lds[128];
    int bx = blockIdx.x, tid = threadIdx.x;
    if (bx < T1_BLOCKS) {
        int c = bx & 63, q = (bx >> 6) & 3, b = bx >> 8;      // all uniform
        if (tid < T1_CS) lds[tid] = vt[b * NPAD + c * T1_CS + tid];
        __syncthreads();
        int x = tid & 63, ry = tid >> 6;
        float fx = (float)x;
        float fy0 = (float)(q * 16 + ry);
        float fy1 = fy0 + 4.f, fy2 = fy0 + 8.f, fy3 = fy0 + 12.f;
        float m0 = FINF, m1 = FINF, m2 = FINF, m3 = FINF;
        #pragma unroll 4
        for (int i = 0; i < T1_CS; i += 2) {
            float4 a = lds[i], g = lds[i + 1];
            float ta = fmaf(a.x, fx, a.z);                     // shared over rows
            float tg = fmaf(g.x, fx, g.z);
            m0 = fminf(m0, fminf(fmaf(a.y, fy0, ta), fmaf(g.y, fy0, tg)));
            m1 = fminf(m1, fminf(fmaf(a.y, fy1, ta), fmaf(g.y, fy1, tg)));
            m2 = fminf(m2, fminf(fmaf(a.y, fy2, ta), fmaf(g.y, fy2, tg)));
            m3 = fminf(m3, fminf(fmaf(a.y, fy3, ta), fmaf(g.y, fy3, tg)));
        }
        float fx2 = fx * fx;
        int y0 = q * 16 + ry;
        unsigned* tp = t1 + (b << 12) + x;
        m0 = fmaxf(fmaf(fy0, fy0, fx2) + m0, 0.f);
        m1 = fmaxf(fmaf(fy1, fy1, fx2) + m1, 0.f);
        m2 = fmaxf(fmaf(fy2, fy2, fx2) + m2, 0.f);
        m3 = fmaxf(fmaf(fy3, fy3, fx2) + m3, 0.f);
        atomicMin(tp + (y0     ) * 64, __float_as_uint(m0));
        atomicMin(tp + (y0 +  4) * 64, __float_as_uint(m1));
        atomicMin(tp + (y0 +  8) * 64, __float_as_uint(m2));
        atomicMin(tp + (y0 + 12) * 64, __float_as_uint(m3));
    } else {
        int t2i = bx - T1_BLOCKS;                              // [0,896)
        int pc = t2i & 31;
        int r  = t2i >> 5;                                     // 0..27
        int g  = r % 7, b = r / 7;                             // uniform
        if (tid < 128) lds[tid] = pl[b * HW + pc * 128 + tid];
        __syncthreads();
        int n0 = g * 1024 + tid;
        const float2* vv = reinterpret_cast<const float2*>(vert) + b * NV;
        float vx[4], vy[4];
        bool  val[4];
        #pragma unroll
        for (int k = 0; k < 4; ++k) {
            int n = n0 + 256 * k;
            val[k] = (n < NV);
            float2 t = val[k] ? vv[n] : make_float2(0.f, 0.f);
            vx[k] = t.x; vy[k] = t.y;
        }
        float mm[4] = {FINF, FINF, FINF, FINF};
        #pragma unroll 4
        for (int j = 0; j < 128; j += 2) {
            float4 a = lds[j], cc = lds[j + 1];
            #pragma unroll
            for (int k = 0; k < 4; ++k) {
                float da = fmaf(a.x,  vx[k], fmaf(a.y,  vy[k], a.z));
                float dc = fmaf(cc.x, vx[k], fmaf(cc.y, vy[k], cc.z));
                mm[k] = fminf(mm[k], fminf(da, dc));
            }
        }
        #pragma unroll
        for (int k = 0; k < 4; ++k) {
            if (val[k]) {
                float m = fmaxf(mm[k] + fmaf(vx[k], vx[k], vy[k] * vy[k]), 0.f);
                atomicMin(&t2[b * NPAD + n0 + 256 * k], __float_as_uint(m));
            }
        }
    }
}

// ---------------------------------------------------------------------------
// Reduce stage 1: sqrt + scale + mask, block-reduce to partials.
__global__ __launch_bounds__(256) void k_red1(const unsigned* __restrict__ t1,
                                              const unsigned* __restrict__ t2,
                                              const int* __restrict__ mask,
                                              float* __restrict__ part) {
    int gid = blockIdx.x * 256 + threadIdx.x;   // 0..44031
    float v = 0.f;
    if (gid < HW * NB) {
        if (mask[gid] > 0)
            v = sqrtf(__uint_as_float(t1[gid])) * (1.0f / 64.0f);
    } else {
        int j = gid - HW * NB;                  // 0..27647
        int bb = j / NPAD;
        int n  = j - bb * NPAD;
        if (n < NV)
            v = sqrtf(__uint_as_float(t2[j])) * (1.0f / 64.0f);
    }
    __shared__ float sbuf[4];
    for (int off = 32; off; off >>= 1) v += __shfl_down(v, off, 64);
    int lane = threadIdx.x & 63, wid = threadIdx.x >> 6;
    if (!lane) sbuf[wid] = v;
    __syncthreads();
    if (wid == 0) {
        v = (lane < 4) ? sbuf[lane] : 0.f;
        v += __shfl_down(v, 2, 64);
        v += __shfl_down(v, 1, 64);
        if (!lane) part[blockIdx.x] = v;
    }
}

// Reduce stage 2: sum partials, write scalar output.
__global__ __launch_bounds__(256) void k_red2(const float* __restrict__ part,
                                              float* __restrict__ out) {
    float v = (threadIdx.x < NRED_BLOCKS) ? part[threadIdx.x] : 0.f;
    __shared__ float sbuf[4];
    for (int off = 32; off; off >>= 1) v += __shfl_down(v, off, 64);
    int lane = threadIdx.x & 63, wid = threadIdx.x >> 6;
    if (!lane) sbuf[wid] = v;
    __syncthreads();
    if (threadIdx.x == 0) out[0] = sbuf[0] + sbuf[1] + sbuf[2] + sbuf[3];
}

extern "C" void kernel_launch(void* const* d_in, const int* in_sizes, int n_in,
                              void* d_out, int out_size, void* d_ws, size_t ws_size,
                              hipStream_t stream) {
    const float* vert = (const float*)d_in[0];
    const int*   mask = (const int*)d_in[1];
    char* ws = (char*)d_ws;
    float4*   vt  = (float4*)(ws + OFF_VT);
    float4*   pl  = (float4*)(ws + OFF_PL);
    unsigned* t1  = (unsigned*)(ws + OFF_T1);
    unsigned* t2  = (unsigned*)(ws + OFF_T2);
    float*    prt = (float*)(ws + OFF_PART);
    float*    out = (float*)d_out;

    k_prep<<<108, 256, 0, stream>>>(vert, mask, vt, pl, t1, t2);
    k_main<<<T1_BLOCKS + T2_BLOCKS, 256, 0, stream>>>(vert, vt, pl, t1, t2);
    k_red1<<<NRED_BLOCKS, 256, 0, stream>>>(t1, t2, mask, prt);
    k_red2<<<1, 256, 0, stream>>>(prt, out);
}